// Round 1
// baseline (287.194 us; speedup 1.0000x reference)
//
#include <hip/hip_runtime.h>
#include <cstdint>
#include <cstddef>

typedef __attribute__((ext_vector_type(8))) short bf16x8;
typedef __attribute__((ext_vector_type(4))) float f32x4;

__device__ __forceinline__ unsigned short f2bf(float x) {
  unsigned int u = __float_as_uint(x);
  u += 0x7FFFu + ((u >> 16) & 1u);   // RNE
  return (unsigned short)(u >> 16);
}

__device__ __forceinline__ void gload_lds16(const void* g, void* l) {
  __builtin_amdgcn_global_load_lds(
      (const __attribute__((address_space(1))) unsigned int*)g,
      (__attribute__((address_space(3))) unsigned int*)l, 16, 0, 0);
}

// ---------------- preprocessing ----------------

__global__ void cast_f32_bf16(const float4* __restrict__ src,
                              ushort4* __restrict__ dst, int n4) {
  int i = blockIdx.x * 256 + threadIdx.x;
  if (i < n4) {
    float4 v = src[i];
    ushort4 o;
    o.x = f2bf(v.x); o.y = f2bf(v.y); o.z = f2bf(v.z); o.w = f2bf(v.w);
    dst[i] = o;
  }
}

// src [K][N] fp32 -> dst [N][K] bf16
__global__ void transpose_cast(const float* __restrict__ src,
                               unsigned short* __restrict__ dst,
                               int K, int N) {
  __shared__ float tile[32][33];
  int nb = blockIdx.x * 32, kb = blockIdx.y * 32;
  int tx = threadIdx.x & 31, ty = threadIdx.x >> 5;  // ty 0..7
#pragma unroll
  for (int r = ty; r < 32; r += 8)
    tile[r][tx] = src[(size_t)(kb + r) * N + nb + tx];
  __syncthreads();
#pragma unroll
  for (int r = ty; r < 32; r += 8)
    dst[(size_t)(nb + r) * K + kb + tx] = f2bf(tile[tx][r]);
}

// bias_tab[h][idx], idx in [0,2047), d = idx-1023
__global__ void bias_tab_kernel(const float* __restrict__ amp,
                                const float* __restrict__ off,
                                const float* __restrict__ sharp,
                                float* __restrict__ tab) {
  int h = blockIdx.x;
  for (int idx = threadIdx.x; idx < 2047; idx += 256) {
    float d = (float)(idx - 1023);
    float acc = 0.f;
#pragma unroll
    for (int k = 0; k < 21; ++k) {
      float dd = d - off[h * 21 + k];
      acc += amp[h * 21 + k] * __expf(-fabsf(sharp[h * 21 + k]) * dd * dd);
    }
    tab[h * 2047 + idx] = acc;
  }
}

// ---------------- NT GEMM: C[M][N] = A[M][K] @ B[N][K]^T ----------------
// MODE 0: bf16 store to C0[M][N]   (Q)
// MODE 1: cols<1024 -> bf16 C0[M][1024] (K); cols>=1024 -> V^T C1[b][h][d][l]
// MODE 2: fp32 store to C0[M][N]   (g)

template <int MODE>
__global__ __launch_bounds__(256)
void gemm_nt(const unsigned short* __restrict__ A,
             const unsigned short* __restrict__ B,
             void* __restrict__ C0, void* __restrict__ C1,
             int M, int N, int K) {
  __shared__ unsigned short sA[128 * 32];
  __shared__ unsigned short sB[128 * 32];
  const int t = threadIdx.x;
  const int lane = t & 63;
  const int w = t >> 6;
  const int wm = (w >> 1) << 6;
  const int wn = (w & 1) << 6;
  const int mtile = blockIdx.y << 7;
  const int ntile = blockIdx.x << 7;
  const int c = lane & 15, g = lane >> 4;
  const int srow = t >> 2;          // 0..63
  const int scol = (t & 3) << 3;    // 0,8,16,24 (elements)
  const unsigned short* aP = A + (size_t)(mtile + srow) * K + scol;
  const unsigned short* bP = B + (size_t)(ntile + srow) * K + scol;
  unsigned short* sAd = &sA[srow * 32 + scol];
  unsigned short* sBd = &sB[srow * 32 + scol];
  f32x4 acc[4][4] = {};

  for (int kt = 0; kt < K; kt += 32) {
    gload_lds16(aP + kt, sAd);
    gload_lds16(aP + (size_t)64 * K + kt, sAd + 64 * 32);
    gload_lds16(bP + kt, sBd);
    gload_lds16(bP + (size_t)64 * K + kt, sBd + 64 * 32);
    __syncthreads();
    bf16x8 af[4], bfr[4];
#pragma unroll
    for (int i = 0; i < 4; ++i) {
      af[i]  = *(const bf16x8*)&sA[(wm + i * 16 + c) * 32 + g * 8];
      bfr[i] = *(const bf16x8*)&sB[(wn + i * 16 + c) * 32 + g * 8];
    }
#pragma unroll
    for (int i = 0; i < 4; ++i)
#pragma unroll
      for (int j = 0; j < 4; ++j)
        acc[i][j] = __builtin_amdgcn_mfma_f32_16x16x32_bf16(af[i], bfr[j], acc[i][j], 0, 0, 0);
    __syncthreads();
  }

  const int row0 = mtile + wm + (g << 2);
  const int col0 = ntile + wn + c;
  if (MODE == 0) {
    unsigned short* q = (unsigned short*)C0;
#pragma unroll
    for (int i = 0; i < 4; ++i)
#pragma unroll
      for (int j = 0; j < 4; ++j) {
        int r = row0 + i * 16, cl = col0 + j * 16;
#pragma unroll
        for (int ri = 0; ri < 4; ++ri)
          q[(size_t)(r + ri) * N + cl] = f2bf(acc[i][j][ri]);
      }
  } else if (MODE == 1) {
    unsigned short* kb = (unsigned short*)C0;
    unsigned short* vt = (unsigned short*)C1;
#pragma unroll
    for (int i = 0; i < 4; ++i)
#pragma unroll
      for (int j = 0; j < 4; ++j) {
        int r = row0 + i * 16, cl = col0 + j * 16;
        if (cl < 1024) {
#pragma unroll
          for (int ri = 0; ri < 4; ++ri)
            kb[(size_t)(r + ri) * 1024 + cl] = f2bf(acc[i][j][ri]);
        } else {
          int d = cl - 1024;
          int hh = d >> 6, dh = d & 63;
          int bb = r >> 10, ll = r & 1023;
          ushort4 pk;
          pk.x = f2bf(acc[i][j][0]);
          pk.y = f2bf(acc[i][j][1]);
          pk.z = f2bf(acc[i][j][2]);
          pk.w = f2bf(acc[i][j][3]);
          *(ushort4*)&vt[((size_t)((bb * 16 + hh) * 64 + dh) << 10) + ll] = pk;
        }
      }
  } else {
    float* gb = (float*)C0;
#pragma unroll
    for (int i = 0; i < 4; ++i)
#pragma unroll
      for (int j = 0; j < 4; ++j) {
        int r = row0 + i * 16, cl = col0 + j * 16;
#pragma unroll
        for (int ri = 0; ri < 4; ++ri)
          gb[(size_t)(r + ri) * N + cl] = acc[i][j][ri];
      }
  }
}

// ---------------- flash attention with TISA bias ----------------
// grid (16 qtiles, 16 heads, 4 batch), 256 threads (4 waves x 16 Q rows)

__global__ __launch_bounds__(256)
void attn_kernel(const unsigned short* __restrict__ qbuf,
                 const unsigned short* __restrict__ kbuf,
                 const unsigned short* __restrict__ vtbuf,
                 const float* __restrict__ biasTab,
                 unsigned short* __restrict__ attnb) {
  const int qt = blockIdx.x, h = blockIdx.y, b = blockIdx.z;
  __shared__ unsigned short sQ[64][72];
  __shared__ unsigned short sK[64][72];
  __shared__ unsigned short sVt[64][72];
  __shared__ unsigned short sP[4][16][72];
  const int t = threadIdx.x, lane = t & 63, w = t >> 6;
  const int c = lane & 15, g = lane >> 4;

  const unsigned short* qsrc = qbuf + (size_t)(b * 1024 + qt * 64) * 1024 + h * 64;
  {
    int r = t >> 3, cc = (t & 7) * 8;
    *(uint4*)&sQ[r][cc]      = *(const uint4*)&qsrc[(size_t)r * 1024 + cc];
    *(uint4*)&sQ[r + 32][cc] = *(const uint4*)&qsrc[(size_t)(r + 32) * 1024 + cc];
  }
  __syncthreads();
  bf16x8 aq0 = *(const bf16x8*)&sQ[w * 16 + c][g * 8];
  bf16x8 aq1 = *(const bf16x8*)&sQ[w * 16 + c][32 + g * 8];

  f32x4 o[4] = {};
  float mrow[4], lrow[4];
#pragma unroll
  for (int ri = 0; ri < 4; ++ri) { mrow[ri] = -1e30f; lrow[ri] = 0.f; }

  const unsigned short* ksrc0 = kbuf + (size_t)(b * 1024) * 1024 + h * 64;
  const unsigned short* vsrc0 = vtbuf + (size_t)((b * 16 + h) * 64) * 1024;
  const float* btab = biasTab + h * 2047;
  const int qrow0 = qt * 64 + w * 16 + g * 4;  // + ri

  for (int kv = 0; kv < 16; ++kv) {
    __syncthreads();
    {
      int r = t >> 3, cc = (t & 7) * 8;
      const unsigned short* ks = ksrc0 + (size_t)(kv * 64) * 1024;
      *(uint4*)&sK[r][cc]      = *(const uint4*)&ks[(size_t)r * 1024 + cc];
      *(uint4*)&sK[r + 32][cc] = *(const uint4*)&ks[(size_t)(r + 32) * 1024 + cc];
      const unsigned short* vs = vsrc0 + kv * 64;
      *(uint4*)&sVt[r][cc]      = *(const uint4*)&vs[(size_t)r * 1024 + cc];
      *(uint4*)&sVt[r + 32][cc] = *(const uint4*)&vs[(size_t)(r + 32) * 1024 + cc];
    }
    __syncthreads();

    f32x4 s[4];
#pragma unroll
    for (int nf = 0; nf < 4; ++nf) {
      bf16x8 b0 = *(const bf16x8*)&sK[nf * 16 + c][g * 8];
      bf16x8 b1 = *(const bf16x8*)&sK[nf * 16 + c][32 + g * 8];
      f32x4 z = {};
      z = __builtin_amdgcn_mfma_f32_16x16x32_bf16(aq0, b0, z, 0, 0, 0);
      z = __builtin_amdgcn_mfma_f32_16x16x32_bf16(aq1, b1, z, 0, 0, 0);
      s[nf] = z;
    }

    float p[4][4], mloc[4];
#pragma unroll
    for (int ri = 0; ri < 4; ++ri) mloc[ri] = -1e30f;
#pragma unroll
    for (int nf = 0; nf < 4; ++nf) {
      int col = kv * 64 + nf * 16 + c;
#pragma unroll
      for (int ri = 0; ri < 4; ++ri) {
        float val = s[nf][ri] * 0.125f + btab[col - (qrow0 + ri) + 1023];
        p[nf][ri] = val;
        mloc[ri] = fmaxf(mloc[ri], val);
      }
    }
#pragma unroll
    for (int off = 1; off < 16; off <<= 1)
#pragma unroll
      for (int ri = 0; ri < 4; ++ri)
        mloc[ri] = fmaxf(mloc[ri], __shfl_xor(mloc[ri], off, 64));

    float alpha[4], lsum[4];
#pragma unroll
    for (int ri = 0; ri < 4; ++ri) {
      float mnew = fmaxf(mrow[ri], mloc[ri]);
      alpha[ri] = __expf(mrow[ri] - mnew);
      mrow[ri] = mnew;
      lsum[ri] = 0.f;
    }
#pragma unroll
    for (int nf = 0; nf < 4; ++nf)
#pragma unroll
      for (int ri = 0; ri < 4; ++ri) {
        float e = __expf(p[nf][ri] - mrow[ri]);
        p[nf][ri] = e;
        lsum[ri] += e;
      }
#pragma unroll
    for (int off = 1; off < 16; off <<= 1)
#pragma unroll
      for (int ri = 0; ri < 4; ++ri)
        lsum[ri] += __shfl_xor(lsum[ri], off, 64);
#pragma unroll
    for (int ri = 0; ri < 4; ++ri) lrow[ri] = lrow[ri] * alpha[ri] + lsum[ri];
#pragma unroll
    for (int nf = 0; nf < 4; ++nf)
#pragma unroll
      for (int ri = 0; ri < 4; ++ri) o[nf][ri] *= alpha[ri];

    // P: C-layout -> LDS -> A-layout (wave-private buffer)
#pragma unroll
    for (int nf = 0; nf < 4; ++nf)
#pragma unroll
      for (int ri = 0; ri < 4; ++ri)
        sP[w][g * 4 + ri][nf * 16 + c] = f2bf(p[nf][ri]);
    bf16x8 ap0 = *(const bf16x8*)&sP[w][c][g * 8];
    bf16x8 ap1 = *(const bf16x8*)&sP[w][c][32 + g * 8];
#pragma unroll
    for (int nf = 0; nf < 4; ++nf) {
      bf16x8 b0 = *(const bf16x8*)&sVt[nf * 16 + c][g * 8];
      bf16x8 b1 = *(const bf16x8*)&sVt[nf * 16 + c][32 + g * 8];
      o[nf] = __builtin_amdgcn_mfma_f32_16x16x32_bf16(ap0, b0, o[nf], 0, 0, 0);
      o[nf] = __builtin_amdgcn_mfma_f32_16x16x32_bf16(ap1, b1, o[nf], 0, 0, 0);
    }
  }

  unsigned short* obase = attnb + (size_t)(b * 1024 + qt * 64 + w * 16 + g * 4) * 1024 + h * 64;
#pragma unroll
  for (int nf = 0; nf < 4; ++nf)
#pragma unroll
    for (int ri = 0; ri < 4; ++ri)
      obase[(size_t)ri * 1024 + nf * 16 + c] = f2bf(o[nf][ri] / lrow[ri]);
}

// ---------------- epilogue: out = a * sigmoid(b) ----------------

__global__ void act_kernel(const float* __restrict__ gbuf,
                           const float* __restrict__ bg,
                           float* __restrict__ out) {
  int idx = blockIdx.x * 256 + threadIdx.x;   // 1M threads, one float4 each
  int i = idx >> 8;
  int j4 = (idx & 255) * 4;
  float4 a  = *(const float4*)&gbuf[(size_t)i * 2048 + j4];
  float4 bb = *(const float4*)&gbuf[(size_t)i * 2048 + 1024 + j4];
  float4 ba  = *(const float4*)&bg[j4];
  float4 bbb = *(const float4*)&bg[1024 + j4];
  float4 r;
  r.x = (a.x + ba.x) / (1.f + __expf(-(bb.x + bbb.x)));
  r.y = (a.y + ba.y) / (1.f + __expf(-(bb.y + bbb.y)));
  r.z = (a.z + ba.z) / (1.f + __expf(-(bb.z + bbb.z)));
  r.w = (a.w + ba.w) / (1.f + __expf(-(bb.w + bbb.w)));
  *(float4*)&out[(size_t)i * 1024 + j4] = r;
}

// ---------------- launch ----------------

extern "C" void kernel_launch(void* const* d_in, const int* in_sizes, int n_in,
                              void* d_out, int out_size, void* d_ws, size_t ws_size,
                              hipStream_t stream) {
  const float* x_q   = (const float*)d_in[0];
  const float* x_kv  = (const float*)d_in[1];
  const float* Wq    = (const float*)d_in[2];
  const float* Wm    = (const float*)d_in[3];
  const float* Wg    = (const float*)d_in[4];
  const float* bg    = (const float*)d_in[5];
  const float* amp   = (const float*)d_in[6];
  const float* off   = (const float*)d_in[7];
  const float* sharp = (const float*)d_in[8];
  float* out = (float*)d_out;

  char* ws = (char*)d_ws;
  size_t o = 0;
  auto alloc = [&](size_t bytes) {
    char* p = ws + o;
    o += (bytes + 255) & ~(size_t)255;
    return p;
  };
  unsigned short* bXq   = (unsigned short*)alloc(4096ull * 1024 * 2);
  unsigned short* bXkv  = (unsigned short*)alloc(4096ull * 1024 * 2);
  unsigned short* bWqT  = (unsigned short*)alloc(1024ull * 1024 * 2);
  unsigned short* bWmT  = (unsigned short*)alloc(2048ull * 1024 * 2);
  unsigned short* bWgT  = (unsigned short*)alloc(2048ull * 1024 * 2);
  float*          biasT = (float*)alloc(16ull * 2047 * 4);
  unsigned short* qbuf  = (unsigned short*)alloc(4096ull * 1024 * 2);
  unsigned short* kbuf  = (unsigned short*)alloc(4096ull * 1024 * 2);
  unsigned short* vtbuf = (unsigned short*)alloc(4096ull * 1024 * 2);
  unsigned short* attnb = (unsigned short*)alloc(4096ull * 1024 * 2);
  float*          gbuf  = (float*)alloc(4096ull * 2048 * 4);
  if (ws_size < o) return;  // workspace too small: fail loudly (out stays poisoned)

  cast_f32_bf16<<<4096, 256, 0, stream>>>((const float4*)x_q,  (ushort4*)bXq,  1024 * 1024);
  cast_f32_bf16<<<4096, 256, 0, stream>>>((const float4*)x_kv, (ushort4*)bXkv, 1024 * 1024);
  transpose_cast<<<dim3(32, 32), 256, 0, stream>>>(Wq, bWqT, 1024, 1024);
  transpose_cast<<<dim3(64, 32), 256, 0, stream>>>(Wm, bWmT, 1024, 2048);
  transpose_cast<<<dim3(64, 32), 256, 0, stream>>>(Wg, bWgT, 1024, 2048);
  bias_tab_kernel<<<16, 256, 0, stream>>>(amp, off, sharp, biasT);

  gemm_nt<0><<<dim3(8, 32),  256, 0, stream>>>(bXq,  bWqT, qbuf, nullptr, 4096, 1024, 1024);
  gemm_nt<1><<<dim3(16, 32), 256, 0, stream>>>(bXkv, bWmT, kbuf, vtbuf,   4096, 2048, 1024);
  attn_kernel<<<dim3(16, 16, 4), 256, 0, stream>>>(qbuf, kbuf, vtbuf, biasT, attnb);
  gemm_nt<2><<<dim3(16, 32), 256, 0, stream>>>(attnb, bWgT, gbuf, nullptr, 4096, 2048, 1024);
  act_kernel<<<4096, 256, 0, stream>>>(gbuf, bg, out);
}

// Round 2
// 237.775 us; speedup vs baseline: 1.2078x; 1.2078x over previous
//
#include <hip/hip_runtime.h>
#include <cstdint>
#include <cstddef>

typedef __attribute__((ext_vector_type(8))) short bf16x8;
typedef __attribute__((ext_vector_type(4))) float f32x4;

#define LOG2E 1.44269504f

__device__ __forceinline__ unsigned short f2bf(float x) {
  unsigned int u = __float_as_uint(x);
  u += 0x7FFFu + ((u >> 16) & 1u);   // RNE
  return (unsigned short)(u >> 16);
}

__device__ __forceinline__ void gload_lds16(const void* g, void* l) {
  __builtin_amdgcn_global_load_lds(
      (const __attribute__((address_space(1))) unsigned int*)g,
      (__attribute__((address_space(3))) unsigned int*)l, 16, 0, 0);
}

// ---------------- preprocessing ----------------

__global__ void cast_f32_bf16(const float4* __restrict__ src,
                              ushort4* __restrict__ dst, int n4) {
  int i = blockIdx.x * 256 + threadIdx.x;
  if (i < n4) {
    float4 v = src[i];
    ushort4 o;
    o.x = f2bf(v.x); o.y = f2bf(v.y); o.z = f2bf(v.z); o.w = f2bf(v.w);
    dst[i] = o;
  }
}

// src [K][N] fp32 -> dst [N][K] bf16
__global__ void transpose_cast(const float* __restrict__ src,
                               unsigned short* __restrict__ dst,
                               int K, int N) {
  __shared__ float tile[32][33];
  int nb = blockIdx.x * 32, kb = blockIdx.y * 32;
  int tx = threadIdx.x & 31, ty = threadIdx.x >> 5;
#pragma unroll
  for (int r = ty; r < 32; r += 8)
    tile[r][tx] = src[(size_t)(kb + r) * N + nb + tx];
  __syncthreads();
#pragma unroll
  for (int r = ty; r < 32; r += 8)
    dst[(size_t)(nb + r) * K + kb + tx] = f2bf(tile[tx][r]);
}

// bias_tab[h][idx] * log2e, idx in [0,2047), d = idx-1023
__global__ void bias_tab_kernel(const float* __restrict__ amp,
                                const float* __restrict__ off,
                                const float* __restrict__ sharp,
                                float* __restrict__ tab) {
  int h = blockIdx.x;
  for (int idx = threadIdx.x; idx < 2047; idx += 256) {
    float d = (float)(idx - 1023);
    float acc = 0.f;
#pragma unroll
    for (int k = 0; k < 21; ++k) {
      float dd = d - off[h * 21 + k];
      acc += amp[h * 21 + k] * __expf(-fabsf(sharp[h * 21 + k]) * dd * dd);
    }
    tab[h * 2047 + idx] = acc * LOG2E;
  }
}

// ---------------- fused QKV GEMM ----------------
// bx<8:  Q = Xq @ WqT^T, scaled by 0.125*log2e, bf16 -> qbuf[4096][1024]
// bx>=8: mem = Xkv @ WmT^T; cols<1024 -> kbuf bf16; cols>=1024 -> vtbuf [b][h][d][l]

__global__ __launch_bounds__(256)
void qkv_gemm(const unsigned short* __restrict__ Xq,
              const unsigned short* __restrict__ Xkv,
              const unsigned short* __restrict__ WqT,
              const unsigned short* __restrict__ WmT,
              unsigned short* __restrict__ qbuf,
              unsigned short* __restrict__ kbuf,
              unsigned short* __restrict__ vtbuf) {
  __shared__ unsigned short sA[128 * 32];
  __shared__ unsigned short sB[128 * 32];
  const int bx = blockIdx.x;
  const bool isQ = bx < 8;
  const int ntile = (isQ ? bx : bx - 8) << 7;
  const unsigned short* A = isQ ? Xq : Xkv;
  const unsigned short* B = (isQ ? WqT : WmT) + (size_t)ntile * 1024;
  const int t = threadIdx.x, lane = t & 63, w = t >> 6;
  const int wm = (w >> 1) << 6, wn = (w & 1) << 6;
  const int mtile = blockIdx.y << 7;
  const int c = lane & 15, g = lane >> 4;
  const int srow = t >> 2, scol = (t & 3) << 3;
  const unsigned short* aP = A + (size_t)(mtile + srow) * 1024 + scol;
  const unsigned short* bP = B + (size_t)srow * 1024 + scol;
  unsigned short* sAd = &sA[srow * 32 + scol];
  unsigned short* sBd = &sB[srow * 32 + scol];
  f32x4 acc[4][4] = {};

  for (int kt = 0; kt < 1024; kt += 32) {
    gload_lds16(aP + kt, sAd);
    gload_lds16(aP + (size_t)64 * 1024 + kt, sAd + 64 * 32);
    gload_lds16(bP + kt, sBd);
    gload_lds16(bP + (size_t)64 * 1024 + kt, sBd + 64 * 32);
    __syncthreads();
    bf16x8 af[4], bfr[4];
#pragma unroll
    for (int i = 0; i < 4; ++i) {
      af[i]  = *(const bf16x8*)&sA[(wm + i * 16 + c) * 32 + g * 8];
      bfr[i] = *(const bf16x8*)&sB[(wn + i * 16 + c) * 32 + g * 8];
    }
#pragma unroll
    for (int i = 0; i < 4; ++i)
#pragma unroll
      for (int j = 0; j < 4; ++j)
        acc[i][j] = __builtin_amdgcn_mfma_f32_16x16x32_bf16(af[i], bfr[j], acc[i][j], 0, 0, 0);
    __syncthreads();
  }

  const int row0 = mtile + wm + (g << 2);
  const int col0 = ntile + wn + c;
  if (isQ) {
#pragma unroll
    for (int i = 0; i < 4; ++i)
#pragma unroll
      for (int j = 0; j < 4; ++j) {
        int r = row0 + i * 16, cl = col0 + j * 16;
#pragma unroll
        for (int ri = 0; ri < 4; ++ri)
          qbuf[(size_t)(r + ri) * 1024 + cl] = f2bf(acc[i][j][ri] * (0.125f * LOG2E));
      }
  } else {
#pragma unroll
    for (int i = 0; i < 4; ++i)
#pragma unroll
      for (int j = 0; j < 4; ++j) {
        int r = row0 + i * 16, cl = col0 + j * 16;
        if (cl < 1024) {
#pragma unroll
          for (int ri = 0; ri < 4; ++ri)
            kbuf[(size_t)(r + ri) * 1024 + cl] = f2bf(acc[i][j][ri]);
        } else {
          int d = cl - 1024;
          int hh = d >> 6, dh = d & 63;
          int bb = r >> 10, ll = r & 1023;
          ushort4 pk;
          pk.x = f2bf(acc[i][j][0]);
          pk.y = f2bf(acc[i][j][1]);
          pk.z = f2bf(acc[i][j][2]);
          pk.w = f2bf(acc[i][j][3]);
          *(ushort4*)&vtbuf[((size_t)((bb * 16 + hh) * 64 + dh) << 10) + ll] = pk;
        }
      }
  }
}

// ---------------- flash attention, no-max softmax, glds double-buffer ----------------
// grid (8 qtiles, 16 heads, 4 batch), 512 threads = 8 waves x 16 Q rows
// LDS chunks (16B) XOR-swizzled: phys_chunk = logical_chunk ^ (row & 7)

__global__ __launch_bounds__(512)
void attn_kernel(const unsigned short* __restrict__ qbuf,
                 const unsigned short* __restrict__ kbuf,
                 const unsigned short* __restrict__ vtbuf,
                 const float* __restrict__ biasTab,
                 unsigned short* __restrict__ attnb) {
  const int qt = blockIdx.x, h = blockIdx.y, b = blockIdx.z;
  __shared__ unsigned short sQ[128 * 64];
  __shared__ unsigned short sK[2][64 * 64];
  __shared__ unsigned short sV[2][64 * 64];
  __shared__ unsigned short sP[8][16 * 64];
  const int t = threadIdx.x, lane = t & 63, w = t >> 6;
  const int c = lane & 15, g = lane >> 4;

  // staging geometry: thread t -> row r (0..63), phys chunk pc, logical chunk ch
  const int r = t >> 3, pc = t & 7, ch = pc ^ (r & 7);

  const unsigned short* qsrc = qbuf + (size_t)(b * 1024 + qt * 128) * 1024 + h * 64;
  const unsigned short* ksrc = kbuf + (size_t)(b * 1024) * 1024 + h * 64;
  const unsigned short* vsrc = vtbuf + (size_t)((b * 16 + h) * 64) * 1024;

  // stage Q (128 rows) + first K/V tile
  gload_lds16(qsrc + (size_t)r * 1024 + ch * 8, &sQ[t * 8]);
  gload_lds16(qsrc + (size_t)(r + 64) * 1024 + ch * 8, &sQ[4096 + t * 8]);
  gload_lds16(ksrc + (size_t)r * 1024 + ch * 8, &sK[0][t * 8]);
  gload_lds16(vsrc + (size_t)r * 1024 + ch * 8, &sV[0][t * 8]);
  __syncthreads();

  const int qrow = w * 16 + c;
  const int qx = (qrow & 7) * 8;
  bf16x8 aq0 = *(const bf16x8*)&sQ[qrow * 64 + ((g * 8) ^ qx)];
  bf16x8 aq1 = *(const bf16x8*)&sQ[qrow * 64 + (((g + 4) * 8) ^ qx)];

  f32x4 o[4] = {};
  float lsum[4] = {0.f, 0.f, 0.f, 0.f};
  const int qrow0 = qt * 128 + w * 16 + g * 4;
  const float* bbase = biasTab + h * 2047 + 1023 + c - qrow0;

  for (int kv = 0; kv < 16; ++kv) {
    const int cur = kv & 1;
    if (kv + 1 < 16) {
      gload_lds16(ksrc + (size_t)((kv + 1) * 64 + r) * 1024 + ch * 8, &sK[1 - cur][t * 8]);
      gload_lds16(vsrc + (size_t)r * 1024 + (kv + 1) * 64 + ch * 8, &sV[1 - cur][t * 8]);
    }

    // S = Q K^T (pre-scaled by 0.125*log2e)
    f32x4 s[4];
#pragma unroll
    for (int nf = 0; nf < 4; ++nf) {
      int krow = nf * 16 + c;
      int kx = (krow & 7) * 8;
      bf16x8 b0 = *(const bf16x8*)&sK[cur][krow * 64 + ((g * 8) ^ kx)];
      bf16x8 b1 = *(const bf16x8*)&sK[cur][krow * 64 + (((g + 4) * 8) ^ kx)];
      f32x4 z = {};
      z = __builtin_amdgcn_mfma_f32_16x16x32_bf16(aq0, b0, z, 0, 0, 0);
      z = __builtin_amdgcn_mfma_f32_16x16x32_bf16(aq1, b1, z, 0, 0, 0);
      s[nf] = z;
    }

    // P = exp2(S + bias), accumulate per-lane row sums, stash P in A-layout LDS
    const float* bk = bbase + kv * 64;
#pragma unroll
    for (int nf = 0; nf < 4; ++nf)
#pragma unroll
      for (int ri = 0; ri < 4; ++ri) {
        float e = exp2f(s[nf][ri] + bk[nf * 16 - ri]);
        lsum[ri] += e;
        int prow = g * 4 + ri;
        sP[w][prow * 64 + (((2 * nf + (c >> 3)) ^ (prow & 7)) * 8) + (c & 7)] = f2bf(e);
      }

    int px = (c & 7) * 8;
    bf16x8 ap0 = *(const bf16x8*)&sP[w][c * 64 + ((g * 8) ^ px)];
    bf16x8 ap1 = *(const bf16x8*)&sP[w][c * 64 + (((g + 4) * 8) ^ px)];
#pragma unroll
    for (int nf = 0; nf < 4; ++nf) {
      int vrow = nf * 16 + c;
      int vx = (vrow & 7) * 8;
      bf16x8 b0 = *(const bf16x8*)&sV[cur][vrow * 64 + ((g * 8) ^ vx)];
      bf16x8 b1 = *(const bf16x8*)&sV[cur][vrow * 64 + (((g + 4) * 8) ^ vx)];
      o[nf] = __builtin_amdgcn_mfma_f32_16x16x32_bf16(ap0, b0, o[nf], 0, 0, 0);
      o[nf] = __builtin_amdgcn_mfma_f32_16x16x32_bf16(ap1, b1, o[nf], 0, 0, 0);
    }
    __syncthreads();
  }

  // final row-sum reduction over the 16 c-lanes, then normalize + store
#pragma unroll
  for (int off = 1; off < 16; off <<= 1)
#pragma unroll
    for (int ri = 0; ri < 4; ++ri)
      lsum[ri] += __shfl_xor(lsum[ri], off, 64);
  float rinv[4];
#pragma unroll
  for (int ri = 0; ri < 4; ++ri) rinv[ri] = 1.0f / lsum[ri];

  unsigned short* obase = attnb + (size_t)(b * 1024 + qt * 128 + w * 16 + g * 4) * 1024 + h * 64;
#pragma unroll
  for (int nf = 0; nf < 4; ++nf)
#pragma unroll
    for (int ri = 0; ri < 4; ++ri)
      obase[(size_t)ri * 1024 + nf * 16 + c] = f2bf(o[nf][ri] * rinv[ri]);
}

// ---------------- output GEMM fused with a*sigmoid(b) ----------------
// tile: 128 M x 64 N-pairs; sB rows 0..63 = Wg cols nb*64.. (a), 64..127 = +1024 (b)
// grid (16, 32); out fp32 [4096][1024]

__global__ __launch_bounds__(256)
void out_gemm(const unsigned short* __restrict__ A,
              const unsigned short* __restrict__ WgT,
              const float* __restrict__ bg,
              float* __restrict__ out) {
  __shared__ unsigned short sA[128 * 32];
  __shared__ unsigned short sB[128 * 32];
  const int nb = blockIdx.x;
  const int mtile = blockIdx.y << 7;
  const int t = threadIdx.x, lane = t & 63, w = t >> 6;
  const int c = lane & 15, g = lane >> 4;
  const int srow = t >> 2, scol = (t & 3) << 3;
  const unsigned short* aP = A + (size_t)(mtile + srow) * 1024 + scol;
  const unsigned short* bP0 = WgT + (size_t)(nb * 64 + srow) * 1024 + scol;
  const unsigned short* bP1 = WgT + (size_t)(1024 + nb * 64 + srow) * 1024 + scol;
  unsigned short* sAd = &sA[srow * 32 + scol];
  unsigned short* sBd = &sB[srow * 32 + scol];
  f32x4 acc[2][8] = {};

  for (int kt = 0; kt < 1024; kt += 32) {
    gload_lds16(aP + kt, sAd);
    gload_lds16(aP + (size_t)64 * 1024 + kt, sAd + 64 * 32);
    gload_lds16(bP0 + kt, sBd);
    gload_lds16(bP1 + kt, sBd + 64 * 32);
    __syncthreads();
    bf16x8 af[2], bfr[8];
#pragma unroll
    for (int i = 0; i < 2; ++i)
      af[i] = *(const bf16x8*)&sA[(w * 32 + i * 16 + c) * 32 + g * 8];
#pragma unroll
    for (int j = 0; j < 8; ++j)
      bfr[j] = *(const bf16x8*)&sB[(j * 16 + c) * 32 + g * 8];
#pragma unroll
    for (int i = 0; i < 2; ++i)
#pragma unroll
      for (int j = 0; j < 8; ++j)
        acc[i][j] = __builtin_amdgcn_mfma_f32_16x16x32_bf16(af[i], bfr[j], acc[i][j], 0, 0, 0);
    __syncthreads();
  }

#pragma unroll
  for (int i = 0; i < 2; ++i) {
    int row0 = mtile + w * 32 + i * 16 + (g << 2);
#pragma unroll
    for (int jj = 0; jj < 4; ++jj) {
      int col = nb * 64 + jj * 16 + c;
      float ba = bg[col];
      float bb = bg[1024 + col];
#pragma unroll
      for (int ri = 0; ri < 4; ++ri) {
        float av = acc[i][jj][ri] + ba;
        float bv = acc[i][jj + 4][ri] + bb;
        out[(size_t)(row0 + ri) * 1024 + col] = av / (1.f + exp2f(-LOG2E * bv));
      }
    }
  }
}

// ---------------- launch ----------------

extern "C" void kernel_launch(void* const* d_in, const int* in_sizes, int n_in,
                              void* d_out, int out_size, void* d_ws, size_t ws_size,
                              hipStream_t stream) {
  const float* x_q   = (const float*)d_in[0];
  const float* x_kv  = (const float*)d_in[1];
  const float* Wq    = (const float*)d_in[2];
  const float* Wm    = (const float*)d_in[3];
  const float* Wg    = (const float*)d_in[4];
  const float* bg    = (const float*)d_in[5];
  const float* amp   = (const float*)d_in[6];
  const float* off   = (const float*)d_in[7];
  const float* sharp = (const float*)d_in[8];
  float* out = (float*)d_out;

  char* ws = (char*)d_ws;
  size_t o = 0;
  auto alloc = [&](size_t bytes) {
    char* p = ws + o;
    o += (bytes + 255) & ~(size_t)255;
    return p;
  };
  unsigned short* bXq   = (unsigned short*)alloc(4096ull * 1024 * 2);
  unsigned short* bXkv  = (unsigned short*)alloc(4096ull * 1024 * 2);
  unsigned short* bWqT  = (unsigned short*)alloc(1024ull * 1024 * 2);
  unsigned short* bWmT  = (unsigned short*)alloc(2048ull * 1024 * 2);
  unsigned short* bWgT  = (unsigned short*)alloc(2048ull * 1024 * 2);
  float*          biasT = (float*)alloc(16ull * 2047 * 4);
  unsigned short* qbuf  = (unsigned short*)alloc(4096ull * 1024 * 2);
  unsigned short* kbuf  = (unsigned short*)alloc(4096ull * 1024 * 2);
  unsigned short* vtbuf = (unsigned short*)alloc(4096ull * 1024 * 2);
  unsigned short* attnb = (unsigned short*)alloc(4096ull * 1024 * 2);
  if (ws_size < o) return;

  cast_f32_bf16<<<4096, 256, 0, stream>>>((const float4*)x_q,  (ushort4*)bXq,  1024 * 1024);
  cast_f32_bf16<<<4096, 256, 0, stream>>>((const float4*)x_kv, (ushort4*)bXkv, 1024 * 1024);
  transpose_cast<<<dim3(32, 32), 256, 0, stream>>>(Wq, bWqT, 1024, 1024);
  transpose_cast<<<dim3(64, 32), 256, 0, stream>>>(Wm, bWmT, 1024, 2048);
  transpose_cast<<<dim3(64, 32), 256, 0, stream>>>(Wg, bWgT, 1024, 2048);
  bias_tab_kernel<<<16, 256, 0, stream>>>(amp, off, sharp, biasT);

  qkv_gemm<<<dim3(24, 32), 256, 0, stream>>>(bXq, bXkv, bWqT, bWmT, qbuf, kbuf, vtbuf);
  attn_kernel<<<dim3(8, 16, 4), 512, 0, stream>>>(qbuf, kbuf, vtbuf, biasT, attnb);
  out_gemm<<<dim3(16, 32), 256, 0, stream>>>(attnb, bWgT, bg, out);
}

// Round 3
// 222.000 us; speedup vs baseline: 1.2937x; 1.0711x over previous
//
#include <hip/hip_runtime.h>
#include <cstdint>
#include <cstddef>

typedef __attribute__((ext_vector_type(8))) short bf16x8;
typedef __attribute__((ext_vector_type(4))) float f32x4;

#define LOG2E 1.44269504f

__device__ __forceinline__ unsigned short f2bf(float x) {
  unsigned int u = __float_as_uint(x);
  u += 0x7FFFu + ((u >> 16) & 1u);   // RNE
  return (unsigned short)(u >> 16);
}

__device__ __forceinline__ void gload_lds16(const void* g, void* l) {
  __builtin_amdgcn_global_load_lds(
      (const __attribute__((address_space(1))) unsigned int*)g,
      (__attribute__((address_space(3))) unsigned int*)l, 16, 0, 0);
}

// ---------------- preprocessing (merged) ----------------

// casts both x_q and x_kv; grid 8192 x 256, first 1M float4 = x_q
__global__ void cast2_f32_bf16(const float4* __restrict__ xq,
                               const float4* __restrict__ xkv,
                               ushort4* __restrict__ dq,
                               ushort4* __restrict__ dkv) {
  int i = blockIdx.x * 256 + threadIdx.x;
  const float4* s;
  ushort4* d;
  if (i < (1 << 20)) { s = xq; d = dq; }
  else { s = xkv + ((1 << 20) * -1); d = dkv - (1 << 20); }  // offset fold
  float4 v = s[i];
  ushort4 o;
  o.x = f2bf(v.x); o.y = f2bf(v.y); o.z = f2bf(v.z); o.w = f2bf(v.w);
  d[i] = o;
}

// z=0: Wq (N=1024), z=1: Wm (N=2048), z=2: Wg (N=2048); K=1024
__global__ void transpose_cast3(const float* __restrict__ Wq,
                                const float* __restrict__ Wm,
                                const float* __restrict__ Wg,
                                unsigned short* __restrict__ dWq,
                                unsigned short* __restrict__ dWm,
                                unsigned short* __restrict__ dWg) {
  __shared__ float tile[32][33];
  int z = blockIdx.z;
  const float* src = z == 0 ? Wq : (z == 1 ? Wm : Wg);
  unsigned short* dst = z == 0 ? dWq : (z == 1 ? dWm : dWg);
  int N = z == 0 ? 1024 : 2048;
  int nb = blockIdx.x * 32, kb = blockIdx.y * 32;
  if (nb >= N) return;
  int tx = threadIdx.x & 31, ty = threadIdx.x >> 5;
#pragma unroll
  for (int r = ty; r < 32; r += 8)
    tile[r][tx] = src[(size_t)(kb + r) * N + nb + tx];
  __syncthreads();
#pragma unroll
  for (int r = ty; r < 32; r += 8)
    dst[(size_t)(nb + r) * 1024 + kb + tx] = f2bf(tile[tx][r]);
}

// bias_tab[h][idx] * log2e, idx in [0,2047), d = idx-1023
__global__ void bias_tab_kernel(const float* __restrict__ amp,
                                const float* __restrict__ off,
                                const float* __restrict__ sharp,
                                float* __restrict__ tab) {
  int h = blockIdx.x;
  for (int idx = threadIdx.x; idx < 2047; idx += 256) {
    float d = (float)(idx - 1023);
    float acc = 0.f;
#pragma unroll
    for (int k = 0; k < 21; ++k) {
      float dd = d - off[h * 21 + k];
      acc += amp[h * 21 + k] * __expf(-fabsf(sharp[h * 21 + k]) * dd * dd);
    }
    tab[h * 2047 + idx] = acc * LOG2E;
  }
}

// ---------------- fused QKV GEMM (double-buffered, prefetch-at-top) ----------------
// bx<8:  Q = Xq @ WqT^T, scaled by 0.125*log2e, bf16 -> qbuf[4096][1024]
// bx>=8: mem = Xkv @ WmT^T; cols<1024 -> kbuf bf16; cols>=1024 -> vtbuf [b][h][d][l]

__global__ __launch_bounds__(256)
void qkv_gemm(const unsigned short* __restrict__ Xq,
              const unsigned short* __restrict__ Xkv,
              const unsigned short* __restrict__ WqT,
              const unsigned short* __restrict__ WmT,
              unsigned short* __restrict__ qbuf,
              unsigned short* __restrict__ kbuf,
              unsigned short* __restrict__ vtbuf) {
  __shared__ unsigned short sA[2][128 * 32];
  __shared__ unsigned short sB[2][128 * 32];
  const int bx = blockIdx.x;
  const bool isQ = bx < 8;
  const int ntile = (isQ ? bx : bx - 8) << 7;
  const unsigned short* A = isQ ? Xq : Xkv;
  const unsigned short* B = (isQ ? WqT : WmT) + (size_t)ntile * 1024;
  const int t = threadIdx.x, lane = t & 63, w = t >> 6;
  const int wm = (w >> 1) << 6, wn = (w & 1) << 6;
  const int mtile = blockIdx.y << 7;
  const int c = lane & 15, g = lane >> 4;
  const int srow = t >> 2, scol = (t & 3) << 3;
  const unsigned short* aP = A + (size_t)(mtile + srow) * 1024 + scol;
  const unsigned short* bP = B + (size_t)srow * 1024 + scol;
  const int lo = srow * 32 + scol;

  gload_lds16(aP, &sA[0][lo]);
  gload_lds16(aP + 64 * 1024, &sA[0][lo + 64 * 32]);
  gload_lds16(bP, &sB[0][lo]);
  gload_lds16(bP + 64 * 1024, &sB[0][lo + 64 * 32]);
  __syncthreads();

  f32x4 acc[4][4] = {};
  for (int kt = 0; kt < 32; ++kt) {
    const int cur = kt & 1;
    if (kt + 1 < 32) {
      const int ko = (kt + 1) * 32;
      gload_lds16(aP + ko, &sA[1 - cur][lo]);
      gload_lds16(aP + 64 * 1024 + ko, &sA[1 - cur][lo + 64 * 32]);
      gload_lds16(bP + ko, &sB[1 - cur][lo]);
      gload_lds16(bP + 64 * 1024 + ko, &sB[1 - cur][lo + 64 * 32]);
    }
    bf16x8 af[4], bfr[4];
#pragma unroll
    for (int i = 0; i < 4; ++i) {
      af[i]  = *(const bf16x8*)&sA[cur][(wm + i * 16 + c) * 32 + g * 8];
      bfr[i] = *(const bf16x8*)&sB[cur][(wn + i * 16 + c) * 32 + g * 8];
    }
#pragma unroll
    for (int i = 0; i < 4; ++i)
#pragma unroll
      for (int j = 0; j < 4; ++j)
        acc[i][j] = __builtin_amdgcn_mfma_f32_16x16x32_bf16(af[i], bfr[j], acc[i][j], 0, 0, 0);
    __syncthreads();
  }

  const int row0 = mtile + wm + (g << 2);
  const int col0 = ntile + wn + c;
  if (isQ) {
#pragma unroll
    for (int i = 0; i < 4; ++i)
#pragma unroll
      for (int j = 0; j < 4; ++j) {
        int r = row0 + i * 16, cl = col0 + j * 16;
#pragma unroll
        for (int ri = 0; ri < 4; ++ri)
          qbuf[(size_t)(r + ri) * 1024 + cl] = f2bf(acc[i][j][ri] * (0.125f * LOG2E));
      }
  } else {
#pragma unroll
    for (int i = 0; i < 4; ++i)
#pragma unroll
      for (int j = 0; j < 4; ++j) {
        int r = row0 + i * 16, cl = col0 + j * 16;
        if (cl < 1024) {
#pragma unroll
          for (int ri = 0; ri < 4; ++ri)
            kbuf[(size_t)(r + ri) * 1024 + cl] = f2bf(acc[i][j][ri]);
        } else {
          int d = cl - 1024;
          int hh = d >> 6, dh = d & 63;
          int bb = r >> 10, ll = r & 1023;
          ushort4 pk;
          pk.x = f2bf(acc[i][j][0]);
          pk.y = f2bf(acc[i][j][1]);
          pk.z = f2bf(acc[i][j][2]);
          pk.w = f2bf(acc[i][j][3]);
          *(ushort4*)&vtbuf[((size_t)((bb * 16 + hh) * 64 + dh) << 10) + ll] = pk;
        }
      }
  }
}

// ---------------- flash attention, no-max softmax, glds double-buffer ----------------
// grid (8 qtiles, 16 heads, 4 batch), 512 threads = 8 waves x 16 Q rows
// LDS chunks (16B) XOR-swizzled: phys_chunk = logical_chunk ^ (row & 7)

__global__ __launch_bounds__(512)
void attn_kernel(const unsigned short* __restrict__ qbuf,
                 const unsigned short* __restrict__ kbuf,
                 const unsigned short* __restrict__ vtbuf,
                 const float* __restrict__ biasTab,
                 unsigned short* __restrict__ attnb) {
  const int qt = blockIdx.x, h = blockIdx.y, b = blockIdx.z;
  __shared__ unsigned short sQ[128 * 64];
  __shared__ unsigned short sK[2][64 * 64];
  __shared__ unsigned short sV[2][64 * 64];
  __shared__ unsigned short sP[8][16 * 64];
  const int t = threadIdx.x, lane = t & 63, w = t >> 6;
  const int c = lane & 15, g = lane >> 4;

  const int r = t >> 3, pc = t & 7, ch = pc ^ (r & 7);

  const unsigned short* qsrc = qbuf + (size_t)(b * 1024 + qt * 128) * 1024 + h * 64;
  const unsigned short* ksrc = kbuf + (size_t)(b * 1024) * 1024 + h * 64;
  const unsigned short* vsrc = vtbuf + (size_t)((b * 16 + h) * 64) * 1024;

  gload_lds16(qsrc + (size_t)r * 1024 + ch * 8, &sQ[t * 8]);
  gload_lds16(qsrc + (size_t)(r + 64) * 1024 + ch * 8, &sQ[4096 + t * 8]);
  gload_lds16(ksrc + (size_t)r * 1024 + ch * 8, &sK[0][t * 8]);
  gload_lds16(vsrc + (size_t)r * 1024 + ch * 8, &sV[0][t * 8]);
  __syncthreads();

  const int qrow = w * 16 + c;
  const int qx = (qrow & 7) * 8;
  bf16x8 aq0 = *(const bf16x8*)&sQ[qrow * 64 + ((g * 8) ^ qx)];
  bf16x8 aq1 = *(const bf16x8*)&sQ[qrow * 64 + (((g + 4) * 8) ^ qx)];

  f32x4 o[4] = {};
  float lsum[4] = {0.f, 0.f, 0.f, 0.f};
  const int qrow0 = qt * 128 + w * 16 + g * 4;
  const float* bbase = biasTab + h * 2047 + 1023 + c - qrow0;

  for (int kv = 0; kv < 16; ++kv) {
    const int cur = kv & 1;
    if (kv + 1 < 16) {
      gload_lds16(ksrc + (size_t)((kv + 1) * 64 + r) * 1024 + ch * 8, &sK[1 - cur][t * 8]);
      gload_lds16(vsrc + (size_t)r * 1024 + (kv + 1) * 64 + ch * 8, &sV[1 - cur][t * 8]);
    }

    f32x4 s[4];
#pragma unroll
    for (int nf = 0; nf < 4; ++nf) {
      int krow = nf * 16 + c;
      int kx = (krow & 7) * 8;
      bf16x8 b0 = *(const bf16x8*)&sK[cur][krow * 64 + ((g * 8) ^ kx)];
      bf16x8 b1 = *(const bf16x8*)&sK[cur][krow * 64 + (((g + 4) * 8) ^ kx)];
      f32x4 z = {};
      z = __builtin_amdgcn_mfma_f32_16x16x32_bf16(aq0, b0, z, 0, 0, 0);
      z = __builtin_amdgcn_mfma_f32_16x16x32_bf16(aq1, b1, z, 0, 0, 0);
      s[nf] = z;
    }

    const float* bk = bbase + kv * 64;
#pragma unroll
    for (int nf = 0; nf < 4; ++nf)
#pragma unroll
      for (int ri = 0; ri < 4; ++ri) {
        float e = exp2f(s[nf][ri] + bk[nf * 16 - ri]);
        lsum[ri] += e;
        int prow = g * 4 + ri;
        sP[w][prow * 64 + (((2 * nf + (c >> 3)) ^ (prow & 7)) * 8) + (c & 7)] = f2bf(e);
      }

    int px = (c & 7) * 8;
    bf16x8 ap0 = *(const bf16x8*)&sP[w][c * 64 + ((g * 8) ^ px)];
    bf16x8 ap1 = *(const bf16x8*)&sP[w][c * 64 + (((g + 4) * 8) ^ px)];
#pragma unroll
    for (int nf = 0; nf < 4; ++nf) {
      int vrow = nf * 16 + c;
      int vx = (vrow & 7) * 8;
      bf16x8 b0 = *(const bf16x8*)&sV[cur][vrow * 64 + ((g * 8) ^ vx)];
      bf16x8 b1 = *(const bf16x8*)&sV[cur][vrow * 64 + (((g + 4) * 8) ^ vx)];
      o[nf] = __builtin_amdgcn_mfma_f32_16x16x32_bf16(ap0, b0, o[nf], 0, 0, 0);
      o[nf] = __builtin_amdgcn_mfma_f32_16x16x32_bf16(ap1, b1, o[nf], 0, 0, 0);
    }
    __syncthreads();
  }

#pragma unroll
  for (int off = 1; off < 16; off <<= 1)
#pragma unroll
    for (int ri = 0; ri < 4; ++ri)
      lsum[ri] += __shfl_xor(lsum[ri], off, 64);
  float rinv[4];
#pragma unroll
  for (int ri = 0; ri < 4; ++ri) rinv[ri] = 1.0f / lsum[ri];

  unsigned short* obase = attnb + (size_t)(b * 1024 + qt * 128 + w * 16 + g * 4) * 1024 + h * 64;
#pragma unroll
  for (int nf = 0; nf < 4; ++nf)
#pragma unroll
    for (int ri = 0; ri < 4; ++ri)
      obase[(size_t)ri * 1024 + nf * 16 + c] = f2bf(o[nf][ri] * rinv[ri]);
}

// ---------------- output GEMM fused with a*sigmoid(b) (double-buffered) ----------------
// tile: 128 M x 64 N-pairs; sB rows 0..63 = Wg cols nb*64.. (a), 64..127 = +1024 (b)
// grid (16, 32); out fp32 [4096][1024]

__global__ __launch_bounds__(256)
void out_gemm(const unsigned short* __restrict__ A,
              const unsigned short* __restrict__ WgT,
              const float* __restrict__ bg,
              float* __restrict__ out) {
  __shared__ unsigned short sA[2][128 * 32];
  __shared__ unsigned short sB[2][128 * 32];
  const int nb = blockIdx.x;
  const int mtile = blockIdx.y << 7;
  const int t = threadIdx.x, lane = t & 63, w = t >> 6;
  const int c = lane & 15, g = lane >> 4;
  const int srow = t >> 2, scol = (t & 3) << 3;
  const unsigned short* aP = A + (size_t)(mtile + srow) * 1024 + scol;
  const unsigned short* bP0 = WgT + (size_t)(nb * 64 + srow) * 1024 + scol;
  const unsigned short* bP1 = WgT + (size_t)(1024 + nb * 64 + srow) * 1024 + scol;
  const int lo = srow * 32 + scol;

  gload_lds16(aP, &sA[0][lo]);
  gload_lds16(aP + 64 * 1024, &sA[0][lo + 64 * 32]);
  gload_lds16(bP0, &sB[0][lo]);
  gload_lds16(bP1, &sB[0][lo + 64 * 32]);
  __syncthreads();

  f32x4 acc[2][8] = {};
  for (int kt = 0; kt < 32; ++kt) {
    const int cur = kt & 1;
    if (kt + 1 < 32) {
      const int ko = (kt + 1) * 32;
      gload_lds16(aP + ko, &sA[1 - cur][lo]);
      gload_lds16(aP + 64 * 1024 + ko, &sA[1 - cur][lo + 64 * 32]);
      gload_lds16(bP0 + ko, &sB[1 - cur][lo]);
      gload_lds16(bP1 + ko, &sB[1 - cur][lo + 64 * 32]);
    }
    bf16x8 af[2], bfr[8];
#pragma unroll
    for (int i = 0; i < 2; ++i)
      af[i] = *(const bf16x8*)&sA[cur][(w * 32 + i * 16 + c) * 32 + g * 8];
#pragma unroll
    for (int j = 0; j < 8; ++j)
      bfr[j] = *(const bf16x8*)&sB[cur][(j * 16 + c) * 32 + g * 8];
#pragma unroll
    for (int i = 0; i < 2; ++i)
#pragma unroll
      for (int j = 0; j < 8; ++j)
        acc[i][j] = __builtin_amdgcn_mfma_f32_16x16x32_bf16(af[i], bfr[j], acc[i][j], 0, 0, 0);
    __syncthreads();
  }

#pragma unroll
  for (int i = 0; i < 2; ++i) {
    int row0 = mtile + w * 32 + i * 16 + (g << 2);
#pragma unroll
    for (int jj = 0; jj < 4; ++jj) {
      int col = nb * 64 + jj * 16 + c;
      float ba = bg[col];
      float bb = bg[1024 + col];
#pragma unroll
      for (int ri = 0; ri < 4; ++ri) {
        float av = acc[i][jj][ri] + ba;
        float bv = acc[i][jj + 4][ri] + bb;
        out[(size_t)(row0 + ri) * 1024 + col] = av / (1.f + exp2f(-LOG2E * bv));
      }
    }
  }
}

// ---------------- launch ----------------

extern "C" void kernel_launch(void* const* d_in, const int* in_sizes, int n_in,
                              void* d_out, int out_size, void* d_ws, size_t ws_size,
                              hipStream_t stream) {
  const float* x_q   = (const float*)d_in[0];
  const float* x_kv  = (const float*)d_in[1];
  const float* Wq    = (const float*)d_in[2];
  const float* Wm    = (const float*)d_in[3];
  const float* Wg    = (const float*)d_in[4];
  const float* bg    = (const float*)d_in[5];
  const float* amp   = (const float*)d_in[6];
  const float* off   = (const float*)d_in[7];
  const float* sharp = (const float*)d_in[8];
  float* out = (float*)d_out;

  char* ws = (char*)d_ws;
  size_t o = 0;
  auto alloc = [&](size_t bytes) {
    char* p = ws + o;
    o += (bytes + 255) & ~(size_t)255;
    return p;
  };
  unsigned short* bXq   = (unsigned short*)alloc(4096ull * 1024 * 2);
  unsigned short* bXkv  = (unsigned short*)alloc(4096ull * 1024 * 2);
  unsigned short* bWqT  = (unsigned short*)alloc(1024ull * 1024 * 2);
  unsigned short* bWmT  = (unsigned short*)alloc(2048ull * 1024 * 2);
  unsigned short* bWgT  = (unsigned short*)alloc(2048ull * 1024 * 2);
  float*          biasT = (float*)alloc(16ull * 2047 * 4);
  unsigned short* qbuf  = (unsigned short*)alloc(4096ull * 1024 * 2);
  unsigned short* kbuf  = (unsigned short*)alloc(4096ull * 1024 * 2);
  unsigned short* vtbuf = (unsigned short*)alloc(4096ull * 1024 * 2);
  unsigned short* attnb = (unsigned short*)alloc(4096ull * 1024 * 2);
  if (ws_size < o) return;

  cast2_f32_bf16<<<8192, 256, 0, stream>>>((const float4*)x_q, (const float4*)x_kv,
                                           (ushort4*)bXq, (ushort4*)bXkv);
  transpose_cast3<<<dim3(64, 32, 3), 256, 0, stream>>>(Wq, Wm, Wg, bWqT, bWmT, bWgT);
  bias_tab_kernel<<<16, 256, 0, stream>>>(amp, off, sharp, biasT);

  qkv_gemm<<<dim3(24, 32), 256, 0, stream>>>(bXq, bXkv, bWqT, bWmT, qbuf, kbuf, vtbuf);
  attn_kernel<<<dim3(8, 16, 4), 512, 0, stream>>>(qbuf, kbuf, vtbuf, biasT, attnb);
  out_gemm<<<dim3(16, 32), 256, 0, stream>>>(attnb, bWgT, bg, out);
}

// Round 4
// 217.574 us; speedup vs baseline: 1.3200x; 1.0203x over previous
//
#include <hip/hip_runtime.h>
#include <cstdint>
#include <cstddef>

typedef __attribute__((ext_vector_type(8))) short bf16x8;
typedef __attribute__((ext_vector_type(4))) float f32x4;

#define LOG2E 1.44269504f

__device__ __forceinline__ unsigned short f2bf(float x) {
  unsigned int u = __float_as_uint(x);
  u += 0x7FFFu + ((u >> 16) & 1u);   // RNE
  return (unsigned short)(u >> 16);
}
__device__ __forceinline__ unsigned short f2bf_trunc(float x) {
  return (unsigned short)(__float_as_uint(x) >> 16);
}

__device__ __forceinline__ void gload_lds16(const void* g, void* l) {
  __builtin_amdgcn_global_load_lds(
      (const __attribute__((address_space(1))) unsigned int*)g,
      (__attribute__((address_space(3))) unsigned int*)l, 16, 0, 0);
}

// ---------------- preprocessing: one merged dispatch ----------------
// blocks [0,8192): cast x_q/x_kv fp32->bf16
// blocks [8192,14336): transpose+cast Wq/Wm/Wg to [N][K] bf16
// blocks [14336,14352): TISA bias table (pre-scaled by log2e)

__global__ void preproc(const float* __restrict__ x_q, const float* __restrict__ x_kv,
                        const float* __restrict__ Wq, const float* __restrict__ Wm,
                        const float* __restrict__ Wg,
                        const float* __restrict__ amp, const float* __restrict__ off,
                        const float* __restrict__ sharp,
                        ushort4* __restrict__ bXq, ushort4* __restrict__ bXkv,
                        unsigned short* __restrict__ dWq, unsigned short* __restrict__ dWm,
                        unsigned short* __restrict__ dWg, float* __restrict__ tab) {
  __shared__ float tile[32][33];
  const int blk = blockIdx.x;
  if (blk < 8192) {
    int i = blk * 256 + threadIdx.x;
    float4 v;
    ushort4* d;
    if (i < (1 << 20)) { v = ((const float4*)x_q)[i]; d = bXq + i; }
    else { int j = i - (1 << 20); v = ((const float4*)x_kv)[j]; d = bXkv + j; }
    ushort4 o;
    o.x = f2bf(v.x); o.y = f2bf(v.y); o.z = f2bf(v.z); o.w = f2bf(v.w);
    *d = o;
  } else if (blk < 14336) {
    int idx = blk - 8192;
    int z = idx >> 11, rem = idx & 2047;
    int bx = rem & 63, by = rem >> 6;
    const float* src = z == 0 ? Wq : (z == 1 ? Wm : Wg);
    unsigned short* dst = z == 0 ? dWq : (z == 1 ? dWm : dWg);
    int N = z == 0 ? 1024 : 2048;
    int nb = bx * 32, kb = by * 32;
    if (nb >= N) return;
    int tx = threadIdx.x & 31, ty = threadIdx.x >> 5;
#pragma unroll
    for (int r = ty; r < 32; r += 8)
      tile[r][tx] = src[(size_t)(kb + r) * N + nb + tx];
    __syncthreads();
#pragma unroll
    for (int r = ty; r < 32; r += 8)
      dst[(size_t)(nb + r) * 1024 + kb + tx] = f2bf(tile[tx][r]);
  } else {
    int h = blk - 14336;
    for (int idx = threadIdx.x; idx < 2047; idx += 256) {
      float d = (float)(idx - 1023);
      float acc = 0.f;
#pragma unroll
      for (int k = 0; k < 21; ++k) {
        float dd = d - off[h * 21 + k];
        acc += amp[h * 21 + k] * __expf(-fabsf(sharp[h * 21 + k]) * dd * dd);
      }
      tab[h * 2047 + idx] = acc * LOG2E;
    }
  }
}

// ---------------- fused QKV GEMM (double-buffered) ----------------

__global__ __launch_bounds__(256)
void qkv_gemm(const unsigned short* __restrict__ Xq,
              const unsigned short* __restrict__ Xkv,
              const unsigned short* __restrict__ WqT,
              const unsigned short* __restrict__ WmT,
              unsigned short* __restrict__ qbuf,
              unsigned short* __restrict__ kbuf,
              unsigned short* __restrict__ vtbuf) {
  __shared__ unsigned short sA[2][128 * 32];
  __shared__ unsigned short sB[2][128 * 32];
  const int bx = blockIdx.x;
  const bool isQ = bx < 8;
  const int ntile = (isQ ? bx : bx - 8) << 7;
  const unsigned short* A = isQ ? Xq : Xkv;
  const unsigned short* B = (isQ ? WqT : WmT) + (size_t)ntile * 1024;
  const int t = threadIdx.x, lane = t & 63, w = t >> 6;
  const int wm = (w >> 1) << 6, wn = (w & 1) << 6;
  const int mtile = blockIdx.y << 7;
  const int c = lane & 15, g = lane >> 4;
  const int srow = t >> 2, scol = (t & 3) << 3;
  const unsigned short* aP = A + (size_t)(mtile + srow) * 1024 + scol;
  const unsigned short* bP = B + (size_t)srow * 1024 + scol;
  const int lo = srow * 32 + scol;

  gload_lds16(aP, &sA[0][lo]);
  gload_lds16(aP + 64 * 1024, &sA[0][lo + 64 * 32]);
  gload_lds16(bP, &sB[0][lo]);
  gload_lds16(bP + 64 * 1024, &sB[0][lo + 64 * 32]);
  __syncthreads();

  f32x4 acc[4][4] = {};
  for (int kt = 0; kt < 32; ++kt) {
    const int cur = kt & 1;
    if (kt + 1 < 32) {
      const int ko = (kt + 1) * 32;
      gload_lds16(aP + ko, &sA[1 - cur][lo]);
      gload_lds16(aP + 64 * 1024 + ko, &sA[1 - cur][lo + 64 * 32]);
      gload_lds16(bP + ko, &sB[1 - cur][lo]);
      gload_lds16(bP + 64 * 1024 + ko, &sB[1 - cur][lo + 64 * 32]);
    }
    bf16x8 af[4], bfr[4];
#pragma unroll
    for (int i = 0; i < 4; ++i) {
      af[i]  = *(const bf16x8*)&sA[cur][(wm + i * 16 + c) * 32 + g * 8];
      bfr[i] = *(const bf16x8*)&sB[cur][(wn + i * 16 + c) * 32 + g * 8];
    }
#pragma unroll
    for (int i = 0; i < 4; ++i)
#pragma unroll
      for (int j = 0; j < 4; ++j)
        acc[i][j] = __builtin_amdgcn_mfma_f32_16x16x32_bf16(af[i], bfr[j], acc[i][j], 0, 0, 0);
    __syncthreads();
  }

  const int row0 = mtile + wm + (g << 2);
  const int col0 = ntile + wn + c;
  if (isQ) {
#pragma unroll
    for (int i = 0; i < 4; ++i)
#pragma unroll
      for (int j = 0; j < 4; ++j) {
        int r = row0 + i * 16, cl = col0 + j * 16;
#pragma unroll
        for (int ri = 0; ri < 4; ++ri)
          qbuf[(size_t)(r + ri) * 1024 + cl] = f2bf(acc[i][j][ri] * (0.125f * LOG2E));
      }
  } else {
#pragma unroll
    for (int i = 0; i < 4; ++i)
#pragma unroll
      for (int j = 0; j < 4; ++j) {
        int r = row0 + i * 16, cl = col0 + j * 16;
        if (cl < 1024) {
#pragma unroll
          for (int ri = 0; ri < 4; ++ri)
            kbuf[(size_t)(r + ri) * 1024 + cl] = f2bf(acc[i][j][ri]);
        } else {
          int d = cl - 1024;
          int hh = d >> 6, dh = d & 63;
          int bb = r >> 10, ll = r & 1023;
          ushort4 pk;
          pk.x = f2bf(acc[i][j][0]);
          pk.y = f2bf(acc[i][j][1]);
          pk.z = f2bf(acc[i][j][2]);
          pk.w = f2bf(acc[i][j][3]);
          *(ushort4*)&vtbuf[((size_t)((bb * 16 + hh) * 64 + dh) << 10) + ll] = pk;
        }
      }
  }
}

// ---------------- flash attention v2: 2D wave tiling, bias-in-C, XCD-local ----------------
// grid (64 = h + 16*b, 8 = qt), 512 threads = 8 waves as 4 row-groups x 2 col-groups.
// All 8 qt-blocks of one (b,h) share id%8 -> same XCD -> K/V L2 reuse.
// LDS 16B chunks XOR-swizzled: phys_chunk = logical_chunk ^ (row & 7).
// sQP: Q during init (aliased), P during the loop.

__global__ __launch_bounds__(512, 4)
void attn_kernel(const unsigned short* __restrict__ qbuf,
                 const unsigned short* __restrict__ kbuf,
                 const unsigned short* __restrict__ vtbuf,
                 const float* __restrict__ biasTab,
                 unsigned short* __restrict__ attnb) {
  const int h = blockIdx.x & 15, b = blockIdx.x >> 4, qt = blockIdx.y;
  __shared__ unsigned short sK[2][64 * 64];
  __shared__ unsigned short sV[2][64 * 64];
  __shared__ unsigned short sQP[128 * 64];
  __shared__ float sLsum[2][128];
  const int t = threadIdx.x, lane = t & 63, w = t >> 6;
  const int c = lane & 15, g = lane >> 4;
  const int rg = w >> 1, cg = w & 1;

  // staging: thread t -> row r, phys chunk t&7 holds logical chunk ch
  const int r = t >> 3, ch = (t & 7) ^ (r & 7);

  const unsigned short* qsrc = qbuf + (size_t)(b * 1024 + qt * 128) * 1024 + h * 64;
  const unsigned short* ksrc = kbuf + (size_t)(b * 1024) * 1024 + h * 64;
  const unsigned short* vsrc = vtbuf + (size_t)((b * 16 + h) * 64) * 1024;

  gload_lds16(qsrc + (size_t)r * 1024 + ch * 8, &sQP[t * 8]);
  gload_lds16(qsrc + (size_t)(r + 64) * 1024 + ch * 8, &sQP[4096 + t * 8]);
  gload_lds16(ksrc + (size_t)r * 1024 + ch * 8, &sK[0][t * 8]);
  gload_lds16(vsrc + (size_t)r * 1024 + ch * 8, &sV[0][t * 8]);
  __syncthreads();

  // Q A-fragments: rows rg*32 + rf*16 + c, k-chunks ks*4+g
  bf16x8 aq[2][2];
#pragma unroll
  for (int rf = 0; rf < 2; ++rf) {
    int row = rg * 32 + rf * 16 + c;
#pragma unroll
    for (int ks = 0; ks < 2; ++ks)
      aq[rf][ks] = *(const bf16x8*)&sQP[row * 64 + (((ks * 4 + g) ^ (row & 7)) * 8)];
  }
  __syncthreads();   // sQP now reusable as sP

  f32x4 o[2][2] = {};
  float lsum[2][4] = {};
  // bias base: rel = (kv*64 + cg*32 + nf*16 + c) - (qt*128 + rg*32 + rf*16 + g*4 + ri) + 1023
  const float* bb = biasTab + h * 2047 + 1023 + cg * 32 + c - qt * 128 - rg * 32 - g * 4;

  for (int kv = 0; kv < 16; ++kv) {
    const int cur = kv & 1;

    // bias -> C-init (issued before prefetch so mfma's waitcnt leaves glds in flight)
    const float* bk = bb + kv * 64;
    f32x4 s[2][2];
#pragma unroll
    for (int rf = 0; rf < 2; ++rf)
#pragma unroll
      for (int nf = 0; nf < 2; ++nf)
#pragma unroll
        for (int ri = 0; ri < 4; ++ri)
          s[rf][nf][ri] = bk[(nf - rf) * 16 - ri];

    if (kv + 1 < 16) {
      gload_lds16(ksrc + (size_t)((kv + 1) * 64 + r) * 1024 + ch * 8, &sK[1 - cur][t * 8]);
      gload_lds16(vsrc + (size_t)r * 1024 + (kv + 1) * 64 + ch * 8, &sV[1 - cur][t * 8]);
    }

    // S = Q K^T + bias (Q pre-scaled by 0.125*log2e)
#pragma unroll
    for (int nf = 0; nf < 2; ++nf) {
      int krow = cg * 32 + nf * 16 + c;
      bf16x8 b0 = *(const bf16x8*)&sK[cur][krow * 64 + (((g) ^ (krow & 7)) * 8)];
      bf16x8 b1 = *(const bf16x8*)&sK[cur][krow * 64 + (((4 + g) ^ (krow & 7)) * 8)];
#pragma unroll
      for (int rf = 0; rf < 2; ++rf) {
        s[rf][nf] = __builtin_amdgcn_mfma_f32_16x16x32_bf16(aq[rf][0], b0, s[rf][nf], 0, 0, 0);
        s[rf][nf] = __builtin_amdgcn_mfma_f32_16x16x32_bf16(aq[rf][1], b1, s[rf][nf], 0, 0, 0);
      }
    }

    // P = exp2(S), accumulate row sums, write P to shared LDS (A-layout source)
#pragma unroll
    for (int rf = 0; rf < 2; ++rf)
#pragma unroll
      for (int nf = 0; nf < 2; ++nf)
#pragma unroll
        for (int ri = 0; ri < 4; ++ri) {
          float e = exp2f(s[rf][nf][ri]);
          lsum[rf][ri] += e;
          int prow = rg * 32 + rf * 16 + g * 4 + ri;
          int chunk = cg * 4 + nf * 2 + (c >> 3);
          sQP[prow * 64 + ((chunk ^ (prow & 7)) * 8) + (c & 7)] = f2bf_trunc(e);
        }
    __syncthreads();   // P visible to cg-buddy waves; also drains K/V prefetch

    // O += P V   (P rows rg*32.., V^T rows = d-cols cg*32..)
    bf16x8 ap[2][2];
#pragma unroll
    for (int rf = 0; rf < 2; ++rf) {
      int row = rg * 32 + rf * 16 + c;
#pragma unroll
      for (int ks = 0; ks < 2; ++ks)
        ap[rf][ks] = *(const bf16x8*)&sQP[row * 64 + (((ks * 4 + g) ^ (row & 7)) * 8)];
    }
#pragma unroll
    for (int df = 0; df < 2; ++df) {
      int vrow = cg * 32 + df * 16 + c;
      bf16x8 b0 = *(const bf16x8*)&sV[cur][vrow * 64 + (((g) ^ (vrow & 7)) * 8)];
      bf16x8 b1 = *(const bf16x8*)&sV[cur][vrow * 64 + (((4 + g) ^ (vrow & 7)) * 8)];
#pragma unroll
      for (int rf = 0; rf < 2; ++rf) {
        o[rf][df] = __builtin_amdgcn_mfma_f32_16x16x32_bf16(ap[rf][0], b0, o[rf][df], 0, 0, 0);
        o[rf][df] = __builtin_amdgcn_mfma_f32_16x16x32_bf16(ap[rf][1], b1, o[rf][df], 0, 0, 0);
      }
    }
    __syncthreads();   // protect sQP (next-iter writes) and sK/sV next buffers
  }

  // combine per-cg partial row sums
#pragma unroll
  for (int off = 1; off < 16; off <<= 1)
#pragma unroll
    for (int rf = 0; rf < 2; ++rf)
#pragma unroll
      for (int ri = 0; ri < 4; ++ri)
        lsum[rf][ri] += __shfl_xor(lsum[rf][ri], off, 64);
  if (c == 0) {
#pragma unroll
    for (int rf = 0; rf < 2; ++rf)
#pragma unroll
      for (int ri = 0; ri < 4; ++ri)
        sLsum[cg][rg * 32 + rf * 16 + g * 4 + ri] = lsum[rf][ri];
  }
  __syncthreads();

  unsigned short* obase = attnb +
      (size_t)(b * 1024 + qt * 128 + rg * 32 + g * 4) * 1024 + h * 64 + cg * 32 + c;
#pragma unroll
  for (int rf = 0; rf < 2; ++rf)
#pragma unroll
    for (int ri = 0; ri < 4; ++ri) {
      int row = rg * 32 + rf * 16 + g * 4 + ri;
      float rinv = 1.0f / (sLsum[0][row] + sLsum[1][row]);
#pragma unroll
      for (int df = 0; df < 2; ++df)
        obase[(size_t)(rf * 16 + ri) * 1024 + df * 16] = f2bf(o[rf][df][ri] * rinv);
    }
}

// ---------------- output GEMM fused with a*sigmoid(b) (double-buffered) ----------------

__global__ __launch_bounds__(256)
void out_gemm(const unsigned short* __restrict__ A,
              const unsigned short* __restrict__ WgT,
              const float* __restrict__ bg,
              float* __restrict__ out) {
  __shared__ unsigned short sA[2][128 * 32];
  __shared__ unsigned short sB[2][128 * 32];
  const int nb = blockIdx.x;
  const int mtile = blockIdx.y << 7;
  const int t = threadIdx.x, lane = t & 63, w = t >> 6;
  const int c = lane & 15, g = lane >> 4;
  const int srow = t >> 2, scol = (t & 3) << 3;
  const unsigned short* aP = A + (size_t)(mtile + srow) * 1024 + scol;
  const unsigned short* bP0 = WgT + (size_t)(nb * 64 + srow) * 1024 + scol;
  const unsigned short* bP1 = WgT + (size_t)(1024 + nb * 64 + srow) * 1024 + scol;
  const int lo = srow * 32 + scol;

  gload_lds16(aP, &sA[0][lo]);
  gload_lds16(aP + 64 * 1024, &sA[0][lo + 64 * 32]);
  gload_lds16(bP0, &sB[0][lo]);
  gload_lds16(bP1, &sB[0][lo + 64 * 32]);
  __syncthreads();

  f32x4 acc[2][8] = {};
  for (int kt = 0; kt < 32; ++kt) {
    const int cur = kt & 1;
    if (kt + 1 < 32) {
      const int ko = (kt + 1) * 32;
      gload_lds16(aP + ko, &sA[1 - cur][lo]);
      gload_lds16(aP + 64 * 1024 + ko, &sA[1 - cur][lo + 64 * 32]);
      gload_lds16(bP0 + ko, &sB[1 - cur][lo]);
      gload_lds16(bP1 + ko, &sB[1 - cur][lo + 64 * 32]);
    }
    bf16x8 af[2], bfr[8];
#pragma unroll
    for (int i = 0; i < 2; ++i)
      af[i] = *(const bf16x8*)&sA[cur][(w * 32 + i * 16 + c) * 32 + g * 8];
#pragma unroll
    for (int j = 0; j < 8; ++j)
      bfr[j] = *(const bf16x8*)&sB[cur][(j * 16 + c) * 32 + g * 8];
#pragma unroll
    for (int i = 0; i < 2; ++i)
#pragma unroll
      for (int j = 0; j < 8; ++j)
        acc[i][j] = __builtin_amdgcn_mfma_f32_16x16x32_bf16(af[i], bfr[j], acc[i][j], 0, 0, 0);
    __syncthreads();
  }

#pragma unroll
  for (int i = 0; i < 2; ++i) {
    int row0 = mtile + w * 32 + i * 16 + (g << 2);
#pragma unroll
    for (int jj = 0; jj < 4; ++jj) {
      int col = nb * 64 + jj * 16 + c;
      float ba = bg[col];
      float bbv = bg[1024 + col];
#pragma unroll
      for (int ri = 0; ri < 4; ++ri) {
        float av = acc[i][jj][ri] + ba;
        float bv = acc[i][jj + 4][ri] + bbv;
        out[(size_t)(row0 + ri) * 1024 + col] = av / (1.f + exp2f(-LOG2E * bv));
      }
    }
  }
}

// ---------------- launch ----------------

extern "C" void kernel_launch(void* const* d_in, const int* in_sizes, int n_in,
                              void* d_out, int out_size, void* d_ws, size_t ws_size,
                              hipStream_t stream) {
  const float* x_q   = (const float*)d_in[0];
  const float* x_kv  = (const float*)d_in[1];
  const float* Wq    = (const float*)d_in[2];
  const float* Wm    = (const float*)d_in[3];
  const float* Wg    = (const float*)d_in[4];
  const float* bg    = (const float*)d_in[5];
  const float* amp   = (const float*)d_in[6];
  const float* off   = (const float*)d_in[7];
  const float* sharp = (const float*)d_in[8];
  float* out = (float*)d_out;

  char* ws = (char*)d_ws;
  size_t o = 0;
  auto alloc = [&](size_t bytes) {
    char* p = ws + o;
    o += (bytes + 255) & ~(size_t)255;
    return p;
  };
  unsigned short* bXq   = (unsigned short*)alloc(4096ull * 1024 * 2);
  unsigned short* bXkv  = (unsigned short*)alloc(4096ull * 1024 * 2);
  unsigned short* bWqT  = (unsigned short*)alloc(1024ull * 1024 * 2);
  unsigned short* bWmT  = (unsigned short*)alloc(2048ull * 1024 * 2);
  unsigned short* bWgT  = (unsigned short*)alloc(2048ull * 1024 * 2);
  float*          biasT = (float*)alloc(16ull * 2047 * 4);
  unsigned short* qbuf  = (unsigned short*)alloc(4096ull * 1024 * 2);
  unsigned short* kbuf  = (unsigned short*)alloc(4096ull * 1024 * 2);
  unsigned short* vtbuf = (unsigned short*)alloc(4096ull * 1024 * 2);
  unsigned short* attnb = (unsigned short*)alloc(4096ull * 1024 * 2);
  if (ws_size < o) return;

  preproc<<<14352, 256, 0, stream>>>(x_q, x_kv, Wq, Wm, Wg, amp, off, sharp,
                                     (ushort4*)bXq, (ushort4*)bXkv,
                                     bWqT, bWmT, bWgT, biasT);
  qkv_gemm<<<dim3(24, 32), 256, 0, stream>>>(bXq, bXkv, bWqT, bWmT, qbuf, kbuf, vtbuf);
  attn_kernel<<<dim3(64, 8), 512, 0, stream>>>(qbuf, kbuf, vtbuf, biasT, attnb);
  out_gemm<<<dim3(16, 32), 256, 0, stream>>>(attnb, bWgT, bg, out);
}